// Round 6
// baseline (435.291 us; speedup 1.0000x reference)
//
#include <hip/hip_runtime.h>
#include <stdint.h>

// Problem constants (from reference)
#define N_CLASSES  10
#define N_TREES    4000
#define DEPTH      6
#define N_INTERNAL 63
#define N_FEATURES 128
#define BATCH      32768
#define LR         0.1f

// Kernel config (R17 = R13 champion geometry + VMEM top-node offload,
// unroll-2 pinned pipeline). Resubmitted R18: round-5 bench was an infra
// failure (container died twice, no compile/test output); vmcnt FIFO
// re-audited by hand-simulation (max 22 outstanding <= 63, no stale-LDS
// window, no spin-waits) -- kernel unchanged.
// R13 (243us) was DS-pipe-saturated (12 b64 + 12 b32 per wave-tile).
// R16 tried to move depths 0-2 into VGPR-held top nodes but the compiler
// SANK the prefetch loads to their use point (VGPR_Count stayed 52 == R13),
// exposing L2 latency every tile (384us). R17 fixes the mechanics:
//  - unroll-2 over tiles with TWO named register sets (tnE/tnO) -> no
//    register copies; consumption is a full body (~2 tiles) after issue.
//  - sched_barrier(0) fences pin issue order (stage < ldt < body end) so
//    the vmcnt FIFO accounting is exact and the scheduler cannot sink the
//    prefetches into the consuming iteration.
//  - phase A's auto-wait for ldt(t) (vmcnt<=12) provably drains stage(t)'s
//    DMA too (FIFO, stage issued first); manual vmcnt(12) guard = backstop.
// DS demand: 6 b64 + 12 b32 ~= 102 cyc/wave-tile -> 408K cyc/CU ~= 170us.
#define BLOCK       256
#define SAMPLES_PB  32
#define T_TILE      16                      // trees per LDS tile (8 KB int2 nodes)
#define N_TILES     (N_TREES / T_TILE)      // 250
#define TILES_PER_CLASS ((N_TREES / N_CLASSES) / T_TILE)   // 25
#define SUMS_STRIDE 11

// prep grid split
#define XPOSE_BLOCKS (BATCH / SAMPLES_PB)           // 1024
#define PACK_BLOCKS  ((N_TREES * 64) / BLOCK)       // 1000

// ws layout:
//   [0, 2.048MB)        nodes by slot, interleaved int2 (feat, thr_bits), 64/tree
//   [2.048MB, 3.072MB)  leaves (64 f32/tree), class-grouped slots
//   [3.072MB, 19.85MB)  x^T: [N_FEATURES][BATCH] f32 (DMA-friendly staging)
// slot = (t%10)*400 + t/10  (class-grouped: 25-tile runs are single-class).
#define WS_NODES_BYTES  ((size_t)N_TREES * 64 * 8)
#define WS_LEAVES_BYTES ((size_t)N_TREES * 64 * 4)
#define WS_XT_BYTES     ((size_t)N_FEATURES * BATCH * 4)

// s_waitcnt immediates (gfx9): vmcnt[3:0] | expcnt<<4 | lgkmcnt<<8, vmcnt[5:4]<<14
// Steady-state guard: keep the 12 newest VMEM ops = lv(t-1)[2] +
// stage(t+1)[2] + ldt(t+1)[8]; drains stage(t)+ldt(t) (phase A usually
// already did via its register auto-waits). Final body: keep lv only.
#define WAITCNT_VM12 0x0F7C
#define WAITCNT_VM2  0x0F72

// Fused prep: blocks [0,1024) transpose x into x^T; blocks [1024,2024) pack
// nodes+leaves into class-grouped slots.
__global__ void prep_kernel(const float* __restrict__ x,
                            const int* __restrict__ features,
                            const float* __restrict__ thresholds,
                            const float* __restrict__ leaves,
                            int2* __restrict__ pn, float* __restrict__ pl,
                            float* __restrict__ xt) {
    const int tid = threadIdx.x;
    if (blockIdx.x < XPOSE_BLOCKS) {
        __shared__ float tile[N_FEATURES * 33];
        const int sample0 = blockIdx.x * SAMPLES_PB;
        const float4* xg = (const float4*)(x + (size_t)sample0 * N_FEATURES);
        #pragma unroll
        for (int k = 0; k < 4; ++k) {
            int e = tid + k * BLOCK;
            int s = e >> 5, f4 = e & 31;
            float4 v = xg[e];
            int f = f4 << 2;
            tile[(f + 0) * 33 + s] = v.x;
            tile[(f + 1) * 33 + s] = v.y;
            tile[(f + 2) * 33 + s] = v.z;
            tile[(f + 3) * 33 + s] = v.w;
        }
        __syncthreads();
        #pragma unroll
        for (int k = 0; k < 4; ++k) {
            int e = tid + k * BLOCK;
            int f = e >> 3, sq = e & 7;
            float4 w;
            w.x = tile[f * 33 + 4 * sq + 0];
            w.y = tile[f * 33 + 4 * sq + 1];
            w.z = tile[f * 33 + 4 * sq + 2];
            w.w = tile[f * 33 + 4 * sq + 3];
            *(float4*)(xt + (size_t)f * BATCH + sample0 + 4 * sq) = w;
        }
    } else {
        int i = (blockIdx.x - XPOSE_BLOCKS) * BLOCK + tid;
        int t = i >> 6, n = i & 63;
        int slot = (t % N_CLASSES) * (N_TREES / N_CLASSES) + (t / N_CLASSES);
        if (n < N_INTERNAL)
            pn[slot * 64 + n] = make_int2(features[t * N_INTERNAL + n],
                                          __float_as_int(thresholds[t * N_INTERNAL + n]));
        pl[slot * 64 + n] = leaves[t * 64 + n];
    }
}

// Standalone pack (mid tier without xt space)
__global__ void pack_kernel(const int* __restrict__ features,
                            const float* __restrict__ thresholds,
                            const float* __restrict__ leaves,
                            int2* __restrict__ pn, float* __restrict__ pl) {
    int i = blockIdx.x * blockDim.x + threadIdx.x;
    int t = i >> 6, n = i & 63;
    if (t < N_TREES) {
        int slot = (t % N_CLASSES) * (N_TREES / N_CLASSES) + (t / N_CLASSES);
        if (n < N_INTERNAL)
            pn[slot * 64 + n] = make_int2(features[t * N_INTERNAL + n],
                                          __float_as_int(thresholds[t * N_INTERNAL + n]));
        pl[slot * 64 + n] = leaves[t * 64 + n];
    }
}

// CK-style addrspace casts for global_load_lds (proven R5..R12).
__device__ __forceinline__ void load_lds_16(const void* g, void* l) {
    const auto* g1 = reinterpret_cast<const __attribute__((address_space(1))) uint32_t*>(
        reinterpret_cast<uintptr_t>(g));
    auto* l3 = reinterpret_cast<__attribute__((address_space(3))) uint32_t*>(
        reinterpret_cast<uintptr_t>(l));
    __builtin_amdgcn_global_load_lds(g1, l3, 16, 0, 0);
}

// Top-7 nodes of one tree, held in VGPRs (loaded via vmcnt pipe).
struct TopNodes { int4 a, b, c; int2 d; };   // nodes 0-1, 2-3, 4-5, 6

// One tile body. WAITIMM must be a literal-constant macro.
// Order inside a body (pinned by sched_barrier(0) fences):
//   [class-boundary flush] -> phaseA(REGS) -> guard vmcnt -> SB ->
//   phaseB(nbuf[BUF]) -> lv consume/issue -> SB -> stage(t+2) -> SB ->
//   ldt(t+2) -> SB
#define GBT_BODY(TILE, BUF, REGS, PREFETCH, WAITIMM)                           \
    do {                                                                       \
        const int tb_ = (TILE);                                                \
        if (tb_ > 0 && (tb_ % TILES_PER_CLASS) == 0) {                         \
            acc += lv0 + lv1; lv0 = 0.f; lv1 = 0.f;                            \
            atomicAdd(&sums[sLocal * SUMS_STRIDE + tb_ / TILES_PER_CLASS - 1], \
                      acc);                                                    \
            acc = 0.f;                                                         \
        }                                                                      \
        int o0_, o1_;                                                          \
        {   /* Phase A: depths 0-2 from VGPR-held top nodes (no DS) */         \
            _Pragma("unroll")                                                  \
            for (int u = 0; u < 2; ++u) {                                      \
                const TopNodes& T = REGS[u];                                   \
                float xa_ = xs[T.a.x * SAMPLES_PB + sLocal];                   \
                int b0_ = xa_ > __int_as_float(T.a.y);                         \
                int f1_ = b0_ ? T.b.x : T.a.z;                                 \
                int t1_ = b0_ ? T.b.y : T.a.w;                                 \
                float xb_ = xs[f1_ * SAMPLES_PB + sLocal];                     \
                int b1_ = xb_ > __int_as_float(t1_);                           \
                int fA_ = b0_ ? T.c.z : T.b.z;   /* n5 : n3 */                 \
                int tA_ = b0_ ? T.c.w : T.b.w;                                 \
                int fB_ = b0_ ? T.d.x : T.c.x;   /* n6 : n4 */                 \
                int tB_ = b0_ ? T.d.y : T.c.y;                                 \
                int f2_ = b1_ ? fB_ : fA_;                                     \
                int t2_ = b1_ ? tB_ : tA_;                                     \
                float xc_ = xs[f2_ * SAMPLES_PB + sLocal];                     \
                int b2_ = xc_ > __int_as_float(t2_);                           \
                int o_ = 7 + 4 * b0_ + 2 * b1_ + b2_;                          \
                if (u == 0) o0_ = o_; else o1_ = o_;                           \
            }                                                                  \
        }                                                                      \
        __builtin_amdgcn_s_waitcnt(WAITIMM);        /* drain this buf's DMA */ \
        __builtin_amdgcn_sched_barrier(0);          /* no ds_read hoisting  */ \
        const int2* nb0_ = &nbuf[BUF][(j * 2 + 0) * 64];                       \
        const int2* nb1_ = &nbuf[BUF][(j * 2 + 1) * 64];                       \
        _Pragma("unroll")                                                      \
        for (int d_ = 3; d_ < DEPTH; ++d_) {        /* Phase B: LDS gather */  \
            int2 na_ = nb0_[o0_];                   /* ds_read_b64 */          \
            int2 nbv_ = nb1_[o1_];                                             \
            float x0_ = xs[na_.x * SAMPLES_PB + sLocal];                       \
            float x1_ = xs[nbv_.x * SAMPLES_PB + sLocal];                      \
            o0_ = 2 * o0_ + 1 + (x0_ > __int_as_float(na_.y) ? 1 : 0);         \
            o1_ = 2 * o1_ + 1 + (x1_ > __int_as_float(nbv_.y) ? 1 : 0);        \
        }                                                                      \
        const size_t slotA_ = (size_t)(tb_ * T_TILE + j * 2);                  \
        acc += lv0 + lv1;                           /* previous tile's pair */ \
        lv0 = pleaves[slotA_ * 64       + (o0_ - N_INTERNAL)];                 \
        lv1 = pleaves[(slotA_ + 1) * 64 + (o1_ - N_INTERNAL)];                 \
        if (PREFETCH) {                                                        \
            __builtin_amdgcn_sched_barrier(0);                                 \
            stage(tb_ + 2, BUF);                    /* DMA for tile t+2 */     \
            __builtin_amdgcn_sched_barrier(0);                                 \
            ldt(tb_ + 2, REGS);                     /* tops for tile t+2 */    \
            __builtin_amdgcn_sched_barrier(0);      /* pin: no sinking */      \
        }                                                                      \
    } while (0)

template <bool XT>
__global__ __launch_bounds__(BLOCK, 4) void gbt_eval(
    const float* __restrict__ x,        // original [BATCH][F] (XT=false path)
    const float* __restrict__ xt,       // x^T [F][BATCH]      (XT=true path)
    const int2*  __restrict__ pnodes,   // [N_TREES][64] int2, class-grouped slots
    const float* __restrict__ pleaves,  // [N_TREES][64], class-grouped slots
    const float* __restrict__ init_out, // [10]
    float*       __restrict__ out)      // [BATCH][10], written directly
{
    __shared__ float xs[N_FEATURES * SAMPLES_PB];       // 16 KB, transposed [f][s]
    __shared__ int2  nbuf[2][T_TILE * 64];              // 2 x 8 KB node tiles
    __shared__ float sums[SAMPLES_PB * SUMS_STRIDE];    // 1.4 KB

    const int tid = threadIdx.x;
    const int sample0 = blockIdx.x * SAMPLES_PB;
    const int lane    = tid & 63;
    const int wv      = tid >> 6;       // wave id 0..3 (wave-uniform)

    if (XT) {
        #pragma unroll
        for (int q = 0; q < 4; ++q) {
            int f0 = wv * 32 + q * 8;
            const char* g = (const char*)(xt
                + (size_t)(f0 + (lane >> 3)) * BATCH + sample0 + (lane & 7) * 4);
            load_lds_16(g, (char*)xs + (size_t)f0 * SAMPLES_PB * 4);
        }
    } else {
        const float4* xg = (const float4*)(x + (size_t)sample0 * N_FEATURES);
        for (int e = tid; e < SAMPLES_PB * (N_FEATURES / 4); e += BLOCK) {
            int s = e >> 5, f4 = e & 31;
            float4 v = xg[e];
            int f = f4 << 2;
            xs[(f + 0) * SAMPLES_PB + s] = v.x;
            xs[(f + 1) * SAMPLES_PB + s] = v.y;
            xs[(f + 2) * SAMPLES_PB + s] = v.z;
            xs[(f + 3) * SAMPLES_PB + s] = v.w;
        }
    }
    for (int i = tid; i < SAMPLES_PB * SUMS_STRIDE; i += BLOCK) sums[i] = 0.f;

    // Stage one 8 KB int2 node tile. Wave wv DMAs chunks 2wv,2wv+1 (trees
    // 4wv..4wv+3) -- exactly the trees its own half-waves read: wave-private.
    auto stage = [&](int tile, int b) {
        const char* g = (const char*)(pnodes + (size_t)(tile * T_TILE) * 64);
        char* lbase = (char*)&nbuf[b][0];
        #pragma unroll
        for (int q = 0; q < 2; ++q) {
            int k = wv * 2 + q;
            load_lds_16(g + k * 1024 + lane * 16, lbase + k * 1024);
        }
    };

    const int sLocal = tid & (SAMPLES_PB - 1);
    const int j      = tid >> 5;        // 0..7 half-wave chunks; trees 2j, 2j+1

    // Top-node loads: VECTOR loads (address divergent by half-wave j -> not
    // scalarized -> vmcnt pipe, no lgkmcnt conflation).
    auto ldt = [&](int tile, TopNodes t2[2]) {
        #pragma unroll
        for (int u = 0; u < 2; ++u) {
            const int4* p = (const int4*)(pnodes
                + (size_t)(tile * T_TILE + j * 2 + u) * 64);
            t2[u].a = p[0];             // nodes 0,1
            t2[u].b = p[1];             // nodes 2,3
            t2[u].c = p[2];             // nodes 4,5
            t2[u].d = ((const int2*)p)[6];  // node 6
        }
    };

    // Prologue: prime both buffers and both register sets; the xs barrier
    // drains everything (one-time cost).
    TopNodes tnE[2], tnO[2];
    stage(0, 0);
    __builtin_amdgcn_sched_barrier(0);
    ldt(0, tnE);
    __builtin_amdgcn_sched_barrier(0);
    stage(1, 1);
    __builtin_amdgcn_sched_barrier(0);
    ldt(1, tnO);
    __syncthreads();   // xs is cross-wave shared: full barrier (drains vmcnt)

    float acc = 0.f, lv0 = 0.f, lv1 = 0.f;

    // Continuous 250-tile loop, unroll-2 (even tiles -> buf0/tnE, odd ->
    // buf1/tnO); class boundary every 25 tiles handled by uniform flush.
    for (int it = 0; it < (N_TILES - 2) / 2; ++it) {       // 124 iterations
        const int t0 = 2 * it;
        GBT_BODY(t0,     0, tnE, true, WAITCNT_VM12);
        GBT_BODY(t0 + 1, 1, tnO, true, WAITCNT_VM12);
    }
    // Peeled final bodies (no prefetch; exact waits).
    GBT_BODY(N_TILES - 2, 0, tnE, false, WAITCNT_VM12);
    GBT_BODY(N_TILES - 1, 1, tnO, false, WAITCNT_VM2);

    acc += lv0 + lv1;               // flush class 9's final pair
    atomicAdd(&sums[sLocal * SUMS_STRIDE + (N_CLASSES - 1)], acc);
    __syncthreads();

    // Sole owner of these samples: plain coalesced stores, init folded in.
    for (int e = tid; e < SAMPLES_PB * N_CLASSES; e += BLOCK) {
        int s = e / N_CLASSES, k = e - s * N_CLASSES;
        out[(size_t)(sample0 + s) * N_CLASSES + k] =
            init_out[k] + LR * sums[s * SUMS_STRIDE + k];
    }
}

// Fallback (ws too small even for nodes+leaves): direct-global gather,
// single block per 32 samples owns all trees (no atomics on out).
__global__ __launch_bounds__(BLOCK, 8) void gbt_eval_global(
    const float* __restrict__ x,
    const int*   __restrict__ features,
    const float* __restrict__ thresholds,
    const float* __restrict__ leaf_values,
    const float* __restrict__ init_out,
    float*       __restrict__ out)
{
    __shared__ float xs[N_FEATURES * SAMPLES_PB];
    __shared__ float sums[SAMPLES_PB * N_CLASSES];
    const int tid = threadIdx.x;
    const int sample0 = blockIdx.x * SAMPLES_PB;
    {
        const float4* xg = (const float4*)(x + (size_t)sample0 * N_FEATURES);
        for (int e = tid; e < SAMPLES_PB * (N_FEATURES / 4); e += BLOCK) {
            int s = e >> 5, f4 = e & 31;
            float4 v = xg[e];
            int f = f4 << 2;
            xs[(f + 0) * SAMPLES_PB + s] = v.x;
            xs[(f + 1) * SAMPLES_PB + s] = v.y;
            xs[(f + 2) * SAMPLES_PB + s] = v.z;
            xs[(f + 3) * SAMPLES_PB + s] = v.w;
        }
    }
    for (int i = tid; i < SAMPLES_PB * N_CLASSES; i += BLOCK) sums[i] = 0.f;
    __syncthreads();
    const int sLocal = tid & (SAMPLES_PB - 1);
    const int j = tid >> 5;
    const int TPT = N_TREES / 8;
    const int t0 = j * TPT;
    float acc[N_CLASSES];
    #pragma unroll
    for (int k = 0; k < N_CLASSES; ++k) acc[k] = 0.f;
    for (int i = 0; i < TPT; i += N_CLASSES) {
        const int tt = t0 + i;
        int idx[N_CLASSES];
        #pragma unroll
        for (int u = 0; u < N_CLASSES; ++u) idx[u] = 0;
        #pragma unroll
        for (int d = 0; d < DEPTH; ++d) {
            #pragma unroll
            for (int u = 0; u < N_CLASSES; ++u) {
                int base = (tt + u) * N_INTERNAL + idx[u];
                float xv = xs[features[base] * SAMPLES_PB + sLocal];
                idx[u] = 2 * idx[u] + 1 + (xv > thresholds[base] ? 1 : 0);
            }
        }
        #pragma unroll
        for (int u = 0; u < N_CLASSES; ++u)
            acc[u] += leaf_values[(size_t)(tt + u) * 64 + idx[u] - N_INTERNAL];
    }
    #pragma unroll
    for (int k = 0; k < N_CLASSES; ++k)
        atomicAdd(&sums[sLocal * N_CLASSES + k], acc[k]);
    __syncthreads();
    for (int e = tid; e < SAMPLES_PB * N_CLASSES; e += BLOCK) {
        int s = e / N_CLASSES, k = e - s * N_CLASSES;
        out[(size_t)(sample0 + s) * N_CLASSES + k] = init_out[k] + LR * sums[e];
    }
}

extern "C" void kernel_launch(void* const* d_in, const int* in_sizes, int n_in,
                              void* d_out, int out_size, void* d_ws, size_t ws_size,
                              hipStream_t stream) {
    const float* x          = (const float*)d_in[0];
    const int*   features   = (const int*)d_in[1];
    const float* thresholds = (const float*)d_in[2];
    const float* leafvals   = (const float*)d_in[3];
    const float* init_out   = (const float*)d_in[4];
    float*       out        = (float*)d_out;

    const int grid = BATCH / SAMPLES_PB;    // 1024 = 256 CU x 4 blocks

    if (ws_size >= WS_NODES_BYTES + WS_LEAVES_BYTES + WS_XT_BYTES) {
        int2*  pn = (int2*)d_ws;
        float* pl = (float*)((char*)d_ws + WS_NODES_BYTES);
        float* xt = (float*)((char*)d_ws + WS_NODES_BYTES + WS_LEAVES_BYTES);
        prep_kernel<<<XPOSE_BLOCKS + PACK_BLOCKS, BLOCK, 0, stream>>>(
            x, features, thresholds, leafvals, pn, pl, xt);
        gbt_eval<true><<<grid, BLOCK, 0, stream>>>(x, xt, pn, pl, init_out, out);
    } else if (ws_size >= WS_NODES_BYTES + WS_LEAVES_BYTES) {
        int2*  pn = (int2*)d_ws;
        float* pl = (float*)((char*)d_ws + WS_NODES_BYTES);
        int n = N_TREES * 64;
        pack_kernel<<<(n + 255) / 256, 256, 0, stream>>>(features, thresholds,
                                                         leafvals, pn, pl);
        gbt_eval<false><<<grid, BLOCK, 0, stream>>>(x, nullptr, pn, pl, init_out, out);
    } else {
        gbt_eval_global<<<BATCH / SAMPLES_PB, BLOCK, 0, stream>>>(
            x, features, thresholds, leafvals, init_out, out);
    }
}